// Round 6
// baseline (138.178 us; speedup 1.0000x reference)
//
#include <hip/hip_runtime.h>
#include <hip/hip_bf16.h>

// ---- problem constants ----
constexpr int NN = 16000, NE = 48000, NF = 32000;
constexpr int ND = 64, NB = 32, NG = 32;
constexpr int HIDN = 256, NCLS = 10;
constexpr int CHB = 32;                       // chunk-blocks per graph in k_ecc
constexpr int EFB = (NE + NF + 255) / 256;    // 313 scatter blocks
constexpr int PREB = EFB;                     // k_pre grid
constexpr int CAPE = 4096, CAPF = 4096;       // bucket capacity (mean 1500/1000)
constexpr float KLOG = 144.26950408889634f;   // 100 * log2(e)
constexpr float DLT  = 9.307710457348151f;    // (2/31) * KLOG
constexpr float INV_DLT = 0.10743849569269015f;
constexpr int HBINS = 39;                     // 4 pad + 32 real + 3 pad (alias-free taps)

// ---- ws word layout (~11 MB of the 268 MB ws) ----
constexpr int ECCF_OFF = 0;                        // [NG*NB*ND]=65536 f32 ecc
constexpr int CUR_OFF  = ECCF_OFF + NG * NB * ND;  // [64] u32 append cursors
constexpr int NOFS_OFF = CUR_OFF + 64;             // [34] i32 node boundaries (+pad)
constexpr int DONE_OFF = NOFS_OFF + 40;            // [32] u32 ecc-done counters
constexpr int DONE2_OFF= DONE_OFF + 32;            // [32] u32 mlp-done counters
constexpr int ER_OFF   = DONE2_OFF + 32;           // float4[NG*CAPE*2]  (4 MB)
constexpr int FR_OFF   = ER_OFF + NG * CAPE * 8;   // float4[NG*CAPF*3]  (6 MB)
constexpr int HB_OFF   = FR_OFF + NG * CAPF * 12;  // [NG*HIDN] f32 hidden acts
constexpr int ZERO_CNT = NG * NB * ND;             // eccf zeroed in k_pre
// memset covers cur..done2: 64 + 40 + 32 + 32 = 168 words (nofs rewritten by k_pre)
constexpr int MS_WORDS = 168;

__device__ __forceinline__ int clamp_node(int n) {
    return ((unsigned)n < (unsigned)NN) ? n : 0;
}
template<bool BF> __device__ __forceinline__ float ldf(const void* p, int i) {
    return BF ? __bfloat162float(((const __hip_bfloat16*)p)[i]) : ((const float*)p)[i];
}
template<bool I64> __device__ __forceinline__ int ldi(const int* p, int i) {
    return I64 ? p[2 * i] : p[i];
}

// per-block dtype self-detection (wave-uniform via ballot)
__device__ __forceinline__ bool detect_bf(const void* xp) {
    const unsigned* xw = (const unsigned*)xp;
    unsigned w = xw[threadIdx.x & 63];
    return __ballot(((w >> 23) & 0xFFu) >= 200u) != 0ull;
}
__device__ __forceinline__ bool detect_i64(const int* eip) {
    const unsigned* eiw = (const unsigned*)eip;
    unsigned o = eiw[2 * (threadIdx.x & 63) + 1];
    return __ballot(o != 0u) == 0ull;
}

// height of premultiplied position p against direction (v0,v1,v2)
__device__ __forceinline__ float dot3w(float4 p, float v0, float v1, float v2) {
    return fmaf(p.z, v2, fmaf(p.y, v1, p.x * v0));
}

// 4-tap delta-histogram sigmoid, alias-free taps (rows (jlo+4)+0..3 distinct).
// Wave-private hist copy: plain LDS read-modify-write (NO f32 LDS atomics —
// they expand to a CAS retry loop; R2 post-mortem).
__device__ __forceinline__ void accum_hist(float h, float s, float* hb) {
    const float KDEC = __builtin_amdgcn_exp2f(-DLT);
    float hkL = fmaf(h, KLOG, KLOG);              // t_j = hkL - j*DLT
    float fl = floorf((hkL - 14.0f) * INV_DLT);
    int jlo = (int)fl + 1;                        // first j with t_j < 14
    if (jlo >= 32) return;                        // everything ~0
    if (jlo < -4) { hb[4 * 64] += s; return; }    // fully saturated: delta at bin 0
    float t0 = fmaf(-(fl + 1.0f), DLT, hkL);      // t at jlo, in [4.69, 14)
    float e  = __builtin_amdgcn_exp2f(t0);
    float s0 = __builtin_amdgcn_rcpf(1.0f + e);  e *= KDEC;
    float s1 = __builtin_amdgcn_rcpf(1.0f + e);  e *= KDEC;
    float s2 = __builtin_amdgcn_rcpf(1.0f + e);
    float* p = hb + (jlo + 4) * 64;
    float v0 = p[0], v1 = p[64], v2 = p[128], v3 = p[192];   // parallel ds_reads
    p[0]   = v0 + s * s0;
    p[64]  = v1 + s * (s1 - s0);
    p[128] = v2 + s * (s2 - s1);
    p[192] = v3 + s * (1.0f - s2);
}

// K0: fused prelude — eccf zero (float4), node boundaries, RESOLVED
// append-scatter with premultiplied endpoint positions.
template<bool BF, bool I64>
__device__ __forceinline__ void pre_body(const void* x, const void* nw,
                                         const int* ei, const int* fc, const int* batch,
                                         const void* ew, const void* fw,
                                         float* wsf, int* wsi, unsigned* cur,
                                         float4* er4, float4* fr4,
                                         unsigned* cnt, unsigned* base) {
    int t = threadIdx.x;
    int gid = blockIdx.x * 256 + t;

    if (gid < ZERO_CNT / 4) {                      // eccf zero, float4
        float4 z; z.x = z.y = z.z = z.w = 0.0f;
        *(float4*)(wsf + ECCF_OFF + gid * 4) = z;
    }

    if (gid < NN) {                                // node range boundaries
        int gn = ldi<I64>(batch, gid) & (NG - 1);
        int gp = (gid > 0) ? (ldi<I64>(batch, gid - 1) & (NG - 1)) : -1;
        for (int gg = gp + 1; gg <= gn; gg++) wsi[NOFS_OFF + gg] = gid;
        if (gid == NN - 1)
            for (int gg = gn + 1; gg <= NG; gg++) wsi[NOFS_OFF + gg] = NN;
    }

    {                                              // append-scatter (all blocks)
        if (t < 64) cnt[t] = 0;
        __syncthreads();
        int id = gid;
        int bin = 0; unsigned rank = 0; bool act = false;
        if (id < NE + NF) {
            if (id < NE) bin = ldi<I64>(batch, clamp_node(ldi<I64>(ei, id))) & 31;
            else bin = 32 + (ldi<I64>(batch, clamp_node(ldi<I64>(fc, id - NE))) & 31);
            act = true;
            rank = atomicAdd(&cnt[bin], 1u);
        }
        __syncthreads();
        if (t < 64) base[t] = cnt[t] ? atomicAdd(&cur[t], cnt[t]) : 0u;
        __syncthreads();
        if (act) {
            int off = (int)(base[bin] + rank);
            if (bin < 32) {
                if (off < CAPE) {
                    int a = clamp_node(ldi<I64>(ei, id));
                    int b = clamp_node(ldi<I64>(ei, NE + id));
                    float wa = ldf<BF>(nw, a), wb = ldf<BF>(nw, b);
                    float4 ra, rb;
                    ra.x = ldf<BF>(x, 3*a)   * wa;
                    ra.y = ldf<BF>(x, 3*a+1) * wa;
                    ra.z = ldf<BF>(x, 3*a+2) * wa;
                    ra.w = ldf<BF>(ew, id);
                    rb.x = ldf<BF>(x, 3*b)   * wb;
                    rb.y = ldf<BF>(x, 3*b+1) * wb;
                    rb.z = ldf<BF>(x, 3*b+2) * wb;
                    rb.w = 0.0f;
                    float4* dst = er4 + ((size_t)bin * CAPE + off) * 2;
                    dst[0] = ra; dst[1] = rb;
                }
            } else {
                if (off < CAPF) {
                    int fid = id - NE;
                    int a = clamp_node(ldi<I64>(fc, fid));
                    int b = clamp_node(ldi<I64>(fc, NF + fid));
                    int c = clamp_node(ldi<I64>(fc, 2 * NF + fid));
                    float wa = ldf<BF>(nw, a), wb = ldf<BF>(nw, b), wc = ldf<BF>(nw, c);
                    float4 qa, qb, qc;
                    qa.x = ldf<BF>(x, 3*a)   * wa;
                    qa.y = ldf<BF>(x, 3*a+1) * wa;
                    qa.z = ldf<BF>(x, 3*a+2) * wa;
                    qa.w = ldf<BF>(fw, fid);
                    qb.x = ldf<BF>(x, 3*b)   * wb;
                    qb.y = ldf<BF>(x, 3*b+1) * wb;
                    qb.z = ldf<BF>(x, 3*b+2) * wb;
                    qb.w = 0.0f;
                    qc.x = ldf<BF>(x, 3*c)   * wc;
                    qc.y = ldf<BF>(x, 3*c+1) * wc;
                    qc.z = ldf<BF>(x, 3*c+2) * wc;
                    qc.w = 0.0f;
                    float4* dst = fr4 + ((size_t)(bin - 32) * CAPF + off) * 3;
                    dst[0] = qa; dst[1] = qb; dst[2] = qc;
                }
            }
        }
    }
}
__global__ __launch_bounds__(256) void k_pre(const void* __restrict__ x,
                                             const void* __restrict__ nw,
                                             const int* __restrict__ ei,
                                             const int* __restrict__ fc,
                                             const int* __restrict__ batch,
                                             const void* __restrict__ ew,
                                             const void* __restrict__ fw,
                                             float* __restrict__ wsf,
                                             int* __restrict__ wsi,
                                             unsigned* __restrict__ cur,
                                             float4* __restrict__ er4,
                                             float4* __restrict__ fr4) {
    __shared__ unsigned cnt[64], base[64];
    bool bf = detect_bf(x), i64 = detect_i64(ei);
    if (bf)  { if (i64) pre_body<true,true >(x,nw,ei,fc,batch,ew,fw,wsf,wsi,cur,er4,fr4,cnt,base);
               else     pre_body<true,false>(x,nw,ei,fc,batch,ew,fw,wsf,wsi,cur,er4,fr4,cnt,base); }
    else     { if (i64) pre_body<false,true >(x,nw,ei,fc,batch,ew,fw,wsf,wsi,cur,er4,fr4,cnt,base);
               else     pre_body<false,false>(x,nw,ei,fc,batch,ew,fw,wsf,wsi,cur,er4,fr4,cnt,base); }
}

// mlp chunk (g, hc): layer 1 over 32 hidden units + flat flush (hc==0) +
// last-block-per-graph layer 2. Scratch red/pr alias the dead hist LDS.
// eccf read via agent-scope atomic loads (written only by coherence-point
// atomics within this kernel). NO __threadfence (R3 lesson).
template<bool BF>
__device__ __forceinline__ void mlp_chunk(int g, int hc, const void* W1, const void* b1,
                                          const void* W2, const void* b2,
                                          const float* eccf, float* hbuf,
                                          unsigned* done2, void* outv,
                                          float* red, float* pr, unsigned* lastflag) {
    int t = threadIdx.x;

    float fl[8];
#pragma unroll
    for (int j = 0; j < 8; j++) {
        unsigned uv = __hip_atomic_load((const unsigned*)&eccf[g * (NB * ND) + t * 8 + j],
                                        __ATOMIC_RELAXED, __HIP_MEMORY_SCOPE_AGENT);
        fl[j] = __uint_as_float(uv);
    }

    if (hc == 0) {                              // flush flat output (once per graph)
        int ob = NG * NCLS + g * (NB * ND) + t * 8;
        if (BF) {
#pragma unroll
            for (int j = 0; j < 8; j++)
                ((__hip_bfloat16*)outv)[ob + j] = __float2bfloat16(fl[j]);
        } else {
#pragma unroll
            for (int j = 0; j < 8; j++)
                ((float*)outv)[ob + j] = fl[j];
        }
    }

    float acc[32];
#pragma unroll
    for (int r = 0; r < 32; r++) acc[r] = 0.0f;
#pragma unroll 4
    for (int r = 0; r < 32; r++) {
        size_t wb = (size_t)(hc * 32 + r) * (NB * ND) + t * 8;
        float wv[8];
        if (BF) {
            uint4 u = *(const uint4*)((const __hip_bfloat16*)W1 + wb);
            wv[0] = __uint_as_float(u.x << 16); wv[1] = __uint_as_float(u.x & 0xffff0000u);
            wv[2] = __uint_as_float(u.y << 16); wv[3] = __uint_as_float(u.y & 0xffff0000u);
            wv[4] = __uint_as_float(u.z << 16); wv[5] = __uint_as_float(u.z & 0xffff0000u);
            wv[6] = __uint_as_float(u.w << 16); wv[7] = __uint_as_float(u.w & 0xffff0000u);
        } else {
            float4 a = *(const float4*)((const float*)W1 + wb);
            float4 b = *(const float4*)((const float*)W1 + wb + 4);
            wv[0]=a.x; wv[1]=a.y; wv[2]=a.z; wv[3]=a.w;
            wv[4]=b.x; wv[5]=b.y; wv[6]=b.z; wv[7]=b.w;
        }
        float s = 0.0f;
#pragma unroll
        for (int j = 0; j < 8; j++) s = fmaf(wv[j], fl[j], s);
        acc[r] = s;
    }

#pragma unroll
    for (int r = 0; r < 32; r++) red[t * 33 + r] = acc[r];
    __syncthreads();
    {
        int r = t >> 3, s8 = t & 7;
        float sum = 0.0f;
#pragma unroll
        for (int i = 0; i < 32; i++) sum += red[(s8 * 32 + i) * 33 + r];
        pr[r * 8 + s8] = sum;
    }
    __syncthreads();
    if (t < 32) {
        float h = ldf<BF>(b1, hc * 32 + t);
#pragma unroll
        for (int s8 = 0; s8 < 8; s8++) h += pr[t * 8 + s8];
        // write-through atomic store: visible at coherence point, no dirty L2 line
        __hip_atomic_store(&hbuf[g * HIDN + hc * 32 + t], fmaxf(h, 0.0f),
                           __ATOMIC_RELAXED, __HIP_MEMORY_SCOPE_AGENT);
    }

    __syncthreads();                            // implies vmcnt(0): stores done
    if (t == 0) {
        unsigned prev = __hip_atomic_fetch_add(&done2[g], 1u, __ATOMIC_RELAXED,
                                               __HIP_MEMORY_SCOPE_AGENT);
        *lastflag = (prev == 7u) ? 1u : 0u;
    }
    __syncthreads();
    if (*lastflag) {
        red[t] = __hip_atomic_load(&hbuf[g * HIDN + t], __ATOMIC_RELAXED,
                                   __HIP_MEMORY_SCOPE_AGENT);
        __syncthreads();
        int w = t >> 6, lane = t & 63;
        for (int c = w; c < NCLS; c += 4) {
            float p = red[lane]        * ldf<BF>(W2, c * HIDN + lane)
                    + red[lane + 64]   * ldf<BF>(W2, c * HIDN + lane + 64)
                    + red[lane + 128]  * ldf<BF>(W2, c * HIDN + lane + 128)
                    + red[lane + 192]  * ldf<BF>(W2, c * HIDN + lane + 192);
#pragma unroll
            for (int off = 32; off >= 1; off >>= 1) p += __shfl_xor(p, off);
            if (lane == 0) {
                float r = p + ldf<BF>(b2, c);
                if (BF) ((__hip_bfloat16*)outv)[g * NCLS + c] = __float2bfloat16(r);
                else    ((float*)outv)[g * NCLS + c] = r;
            }
        }
    }
}

// K1: ecc via wave-private LDS delta-histograms (4 copies, plain RMW),
// gather-free from premultiplied records; FUSED per-graph MLP tail gated
// on done[g]==32 (relaxed agent atomics; bounded s_sleep spin; grid fully
// co-resident at 4 blocks/CU so spin is deadlock-free).
template<bool BF>
__device__ __forceinline__ void ecc_body(const void* xx, const void* nw, const void* vv,
                                         const int* wsi, const unsigned* cur,
                                         float* eccf, const float4* er4,
                                         const float4* fr4, float* hist,
                                         const void* W1, const void* b1,
                                         const void* W2, const void* b2,
                                         float* hbuf, unsigned* done,
                                         unsigned* done2, void* outv,
                                         unsigned* lastflag) {
    int t = threadIdx.x;
    int d = t & 63;
    int w = __builtin_amdgcn_readfirstlane(t) >> 6;
    int g  = blockIdx.x >> 5;                 // / CHB
    int cb = blockIdx.x & (CHB - 1);
    int sid = cb * 4 + w;
    const int S = CHB * 4;                    // 128 streams per graph

    float v0 = ldf<BF>(vv, d), v1 = ldf<BF>(vv, ND + d), v2 = ldf<BF>(vv, 2 * ND + d);

    float4* h4 = (float4*)hist;
    const int Q = HBINS * 16;                 // 624 float4 per copy
    float4 z; z.x = z.y = z.z = z.w = 0.0f;
    for (int j = t; j < 4 * Q; j += 256) h4[j] = z;
    __syncthreads();

    float* hb = hist + w * (HBINS * 64) + d;  // wave-private copy, lane-owned column

    // nodes (+1): heights from x,nw directly (uniform loads), unroll 2
    int ns = wsi[NOFS_OFF + g], nend = wsi[NOFS_OFF + g + 1];
    int i = ns + sid;
    for (; i + S < nend; i += 2 * S) {
        int j = i + S;
        float a0 = ldf<BF>(xx, 3*i), a1 = ldf<BF>(xx, 3*i+1), a2 = ldf<BF>(xx, 3*i+2);
        float wa = ldf<BF>(nw, i);
        float b0 = ldf<BF>(xx, 3*j), b1v = ldf<BF>(xx, 3*j+1), b2v = ldf<BF>(xx, 3*j+2);
        float wb = ldf<BF>(nw, j);
        accum_hist(fmaf(a2, v2, fmaf(a1, v1, a0 * v0)) * wa, 1.0f, hb);
        accum_hist(fmaf(b2v, v2, fmaf(b1v, v1, b0 * v0)) * wb, 1.0f, hb);
    }
    for (; i < nend; i += S) {
        float a0 = ldf<BF>(xx, 3*i), a1 = ldf<BF>(xx, 3*i+1), a2 = ldf<BF>(xx, 3*i+2);
        float wa = ldf<BF>(nw, i);
        accum_hist(fmaf(a2, v2, fmaf(a1, v1, a0 * v0)) * wa, 1.0f, hb);
    }

    // edges (-1): 2 float4 per record, unroll 2
    int ecnt = min((int)cur[g], CAPE);
    const float4* eg = er4 + (size_t)g * CAPE * 2;
    i = sid;
    for (; i + S < ecnt; i += 2 * S) {
        float4 pa1 = eg[2*i],       pb1 = eg[2*i + 1];
        float4 pa2 = eg[2*(i+S)],   pb2 = eg[2*(i+S) + 1];
        float h1 = fmaxf(dot3w(pa1, v0, v1, v2), dot3w(pb1, v0, v1, v2)) * pa1.w;
        float h2 = fmaxf(dot3w(pa2, v0, v1, v2), dot3w(pb2, v0, v1, v2)) * pa2.w;
        accum_hist(h1, -1.0f, hb);
        accum_hist(h2, -1.0f, hb);
    }
    for (; i < ecnt; i += S) {
        float4 pa = eg[2*i], pb = eg[2*i + 1];
        accum_hist(fmaxf(dot3w(pa, v0, v1, v2), dot3w(pb, v0, v1, v2)) * pa.w,
                   -1.0f, hb);
    }

    // faces (+1): 3 float4 per record, unroll 2
    int fcnt = min((int)cur[32 + g], CAPF);
    const float4* fg = fr4 + (size_t)g * CAPF * 3;
    i = sid;
    for (; i + S < fcnt; i += 2 * S) {
        float4 qa1 = fg[3*i], qb1 = fg[3*i + 1], qc1 = fg[3*i + 2];
        float4 qa2 = fg[3*(i+S)], qb2 = fg[3*(i+S) + 1], qc2 = fg[3*(i+S) + 2];
        float h1 = fmaxf(fmaxf(dot3w(qa1, v0, v1, v2), dot3w(qb1, v0, v1, v2)),
                         dot3w(qc1, v0, v1, v2)) * qa1.w;
        float h2 = fmaxf(fmaxf(dot3w(qa2, v0, v1, v2), dot3w(qb2, v0, v1, v2)),
                         dot3w(qc2, v0, v1, v2)) * qa2.w;
        accum_hist(h1, 1.0f, hb);
        accum_hist(h2, 1.0f, hb);
    }
    for (; i < fcnt; i += S) {
        float4 qa = fg[3*i], qb = fg[3*i + 1], qc = fg[3*i + 2];
        accum_hist(fmaxf(fmaxf(dot3w(qa, v0, v1, v2), dot3w(qb, v0, v1, v2)),
                         dot3w(qc, v0, v1, v2)) * qa.w, 1.0f, hb);
    }

    __syncthreads();
    // collapse 4 wave copies into copy 0 (float4)
    for (int o = t; o < Q; o += 256) {
        float4 A = h4[o], B = h4[Q + o], C = h4[2*Q + o], D = h4[3*Q + o];
        A.x += B.x + C.x + D.x;  A.y += B.y + C.y + D.y;
        A.z += B.z + C.z + D.z;  A.w += B.w + C.w + D.w;
        h4[o] = A;
    }
    __syncthreads();
    // parallel segmented prefix: wave w owns bins [8w, 8w+8)
    {
        float* segw = hist + HBINS * 64;
        float run = 0.0f, pre[8];
#pragma unroll
        for (int jj = 0; jj < 8; jj++) {
            run += hist[(4 + w * 8 + jj) * 64 + d];
            pre[jj] = run;
        }
        float padb = hist[d] + hist[64 + d] + hist[128 + d] + hist[192 + d];
        segw[w * 64 + d] = run;
        __syncthreads();
        float base = padb;
#pragma unroll
        for (int u = 0; u < 3; u++) if (u < w) base += segw[u * 64 + d];
        float* eb = eccf + g * (NB * ND) + d;
#pragma unroll
        for (int jj = 0; jj < 8; jj++)
            unsafeAtomicAdd(eb + (w * 8 + jj) * 64, base + pre[jj]);
    }

    // ---- fused MLP tail ----
    // ensure this block's eccf atomics completed before signaling
    asm volatile("s_waitcnt vmcnt(0)" ::: "memory");
    __syncthreads();
    if (t == 0) {
        __hip_atomic_fetch_add(&done[g], 1u, __ATOMIC_RELAXED,
                               __HIP_MEMORY_SCOPE_AGENT);
    }
    if (cb < 8) {
        if (t == 0) {
            // bounded spin: co-residency (4 blocks/CU, grid 1024) guarantees progress
            for (int it = 0; it < (1 << 24); ++it) {
                if (__hip_atomic_load(&done[g], __ATOMIC_RELAXED,
                                      __HIP_MEMORY_SCOPE_AGENT) >= 32u) break;
                __builtin_amdgcn_s_sleep(2);
            }
        }
        __syncthreads();
        // hist is dead; alias as mlp scratch: red[256*33]=8448, pr[256]
        mlp_chunk<BF>(g, cb, W1, b1, W2, b2, eccf, hbuf, done2, outv,
                      hist, hist + 8448, lastflag);
    }
}
__global__ __launch_bounds__(256, 4) void k_ecc(const void* __restrict__ x,
                                                const void* __restrict__ nw,
                                                const void* __restrict__ v,
                                                const int* __restrict__ wsi,
                                                const unsigned* __restrict__ cur,
                                                float* __restrict__ eccf,
                                                const float4* __restrict__ er4,
                                                const float4* __restrict__ fr4,
                                                const void* __restrict__ W1,
                                                const void* __restrict__ b1,
                                                const void* __restrict__ W2,
                                                const void* __restrict__ b2,
                                                float* __restrict__ hbuf,
                                                unsigned* __restrict__ done,
                                                unsigned* __restrict__ done2,
                                                void* __restrict__ outv) {
    __shared__ float hist[4 * HBINS * 64];         // 39.9 KB; 4 blocks/CU
    __shared__ unsigned lastflag;
    if (detect_bf(x)) ecc_body<true >(x, nw, v, wsi, cur, eccf, er4, fr4, hist,
                                      W1, b1, W2, b2, hbuf, done, done2, outv, &lastflag);
    else              ecc_body<false>(x, nw, v, wsi, cur, eccf, er4, fr4, hist,
                                      W1, b1, W2, b2, hbuf, done, done2, outv, &lastflag);
}

extern "C" void kernel_launch(void* const* d_in, const int* in_sizes, int n_in,
                              void* d_out, int out_size, void* d_ws, size_t ws_size,
                              hipStream_t stream) {
    const void* x  = d_in[0];
    const void* nw = d_in[1];
    const void* ew = d_in[2];
    const void* fw = d_in[3];
    const void* v  = d_in[4];
    const void* W1 = d_in[5];
    const void* b1 = d_in[6];
    const void* W2 = d_in[7];
    const void* b2 = d_in[8];
    const int* ei    = (const int*)d_in[9];
    const int* fc    = (const int*)d_in[10];
    const int* batch = (const int*)d_in[11];

    float*    wsf = (float*)d_ws;
    unsigned* wsu = (unsigned*)d_ws;
    int*      wsi = (int*)d_ws;
    float*    eccf = wsf + ECCF_OFF;
    unsigned* cur  = wsu + CUR_OFF;
    unsigned* done = wsu + DONE_OFF;
    unsigned* done2= wsu + DONE2_OFF;
    float*    hbuf = wsf + HB_OFF;
    float4*   er4  = (float4*)(wsf + ER_OFF);
    float4*   fr4  = (float4*)(wsf + FR_OFF);

    // zero cursors + done counters (672 B)
    hipMemsetAsync((char*)d_ws + (size_t)CUR_OFF * 4, 0, MS_WORDS * 4, stream);

    k_pre<<<PREB, 256, 0, stream>>>(x, nw, ei, fc, batch, ew, fw, wsf, wsi, cur, er4, fr4);
    k_ecc<<<NG * CHB, 256, 0, stream>>>(x, nw, v, wsi, cur, eccf, er4, fr4,
                                        W1, b1, W2, b2, hbuf, done, done2, d_out);
}

// Round 8
// 115.588 us; speedup vs baseline: 1.1954x; 1.1954x over previous
//
#include <hip/hip_runtime.h>
#include <hip/hip_bf16.h>

// ---- problem constants ----
constexpr int NN = 16000, NE = 48000, NF = 32000;
constexpr int ND = 64, NB = 32, NG = 32;
constexpr int HIDN = 256, NCLS = 10;
constexpr int CHB = 32;                       // chunk-blocks per graph in k_ecc
constexpr int EFB = (NE + NF + 255) / 256;    // 313 scatter blocks
constexpr int PREB = EFB;                     // k_pre grid
constexpr int CAPE = 4096, CAPF = 4096;       // bucket capacity (mean 1500/1000)
constexpr float KLOG = 144.26950408889634f;   // 100 * log2(e)
constexpr float DLT  = 9.307710457348151f;    // (2/31) * KLOG
constexpr float INV_DLT = 0.10743849569269015f;
constexpr int HBINS = 39;                     // 4 pad + 32 real + 3 pad (alias-free taps)

// ---- ws word layout (~11 MB of the 268 MB ws) ----
constexpr int ECCF_OFF = 0;                        // [NG*NB*ND]=65536 f32 ecc
constexpr int CUR_OFF  = ECCF_OFF + NG * NB * ND;  // [64] u32 append cursors
constexpr int NOFS_OFF = CUR_OFF + 64;             // [34] i32 node boundaries (+pad)
constexpr int DONE_OFF = NOFS_OFF + 40;            // [32] u32 mlp done counters
constexpr int ER_OFF   = DONE_OFF + 32;            // float4[NG*CAPE*2]  (4 MB)
constexpr int FR_OFF   = ER_OFF + NG * CAPE * 8;   // float4[NG*CAPF*3]  (6 MB)
constexpr int HB_OFF   = FR_OFF + NG * CAPF * 12;  // [NG*HIDN] f32 hidden acts
constexpr int ZERO_CNT = NG * NB * ND;             // eccf zeroed in k_pre
// memset covers cur(64) + nofs(40) + done(32) = 136 words
constexpr int MS_WORDS = 136;

__device__ __forceinline__ int clamp_node(int n) {
    return ((unsigned)n < (unsigned)NN) ? n : 0;
}
template<bool BF> __device__ __forceinline__ float ldf(const void* p, int i) {
    return BF ? __bfloat162float(((const __hip_bfloat16*)p)[i]) : ((const float*)p)[i];
}
template<bool I64> __device__ __forceinline__ int ldi(const int* p, int i) {
    return I64 ? p[2 * i] : p[i];
}

// per-block dtype self-detection (wave-uniform via ballot)
__device__ __forceinline__ bool detect_bf(const void* xp) {
    const unsigned* xw = (const unsigned*)xp;
    unsigned w = xw[threadIdx.x & 63];
    return __ballot(((w >> 23) & 0xFFu) >= 200u) != 0ull;
}
__device__ __forceinline__ bool detect_i64(const int* eip) {
    const unsigned* eiw = (const unsigned*)eip;
    unsigned o = eiw[2 * (threadIdx.x & 63) + 1];
    return __ballot(o != 0u) == 0ull;
}

// height of premultiplied position p against direction (v0,v1,v2)
__device__ __forceinline__ float dot3w(float4 p, float v0, float v1, float v2) {
    return fmaf(p.z, v2, fmaf(p.y, v1, p.x * v0));
}

// 4-tap delta-histogram sigmoid, alias-free taps (rows (jlo+4)+0..3 distinct).
// Wave-private hist copy: plain LDS read-modify-write (NO f32 LDS atomics —
// they expand to a CAS retry loop; R2 post-mortem).
__device__ __forceinline__ void accum_hist(float h, float s, float* hb) {
    const float KDEC = __builtin_amdgcn_exp2f(-DLT);
    float hkL = fmaf(h, KLOG, KLOG);              // t_j = hkL - j*DLT
    float fl = floorf((hkL - 14.0f) * INV_DLT);
    int jlo = (int)fl + 1;                        // first j with t_j < 14
    if (jlo >= 32) return;                        // everything ~0
    if (jlo < -4) { hb[4 * 64] += s; return; }    // fully saturated: delta at bin 0
    float t0 = fmaf(-(fl + 1.0f), DLT, hkL);      // t at jlo, in [4.69, 14)
    float e  = __builtin_amdgcn_exp2f(t0);
    float s0 = __builtin_amdgcn_rcpf(1.0f + e);  e *= KDEC;
    float s1 = __builtin_amdgcn_rcpf(1.0f + e);  e *= KDEC;
    float s2 = __builtin_amdgcn_rcpf(1.0f + e);
    float* p = hb + (jlo + 4) * 64;
    float v0 = p[0], v1 = p[64], v2 = p[128], v3 = p[192];   // parallel ds_reads
    p[0]   = v0 + s * s0;
    p[64]  = v1 + s * (s1 - s0);
    p[128] = v2 + s * (s2 - s1);
    p[192] = v3 + s * (1.0f - s2);
}

// K0: fused prelude — eccf zero (float4), node boundaries, RESOLVED
// append-scatter with premultiplied endpoint positions.
template<bool BF, bool I64>
__device__ __forceinline__ void pre_body(const void* x, const void* nw,
                                         const int* ei, const int* fc, const int* batch,
                                         const void* ew, const void* fw,
                                         float* wsf, int* wsi, unsigned* cur,
                                         float4* er4, float4* fr4,
                                         unsigned* cnt, unsigned* base) {
    int t = threadIdx.x;
    int gid = blockIdx.x * 256 + t;

    if (gid < ZERO_CNT / 4) {                      // eccf zero, float4
        float4 z; z.x = z.y = z.z = z.w = 0.0f;
        *(float4*)(wsf + ECCF_OFF + gid * 4) = z;
    }

    if (gid < NN) {                                // node range boundaries
        int gn = ldi<I64>(batch, gid) & (NG - 1);
        int gp = (gid > 0) ? (ldi<I64>(batch, gid - 1) & (NG - 1)) : -1;
        for (int gg = gp + 1; gg <= gn; gg++) wsi[NOFS_OFF + gg] = gid;
        if (gid == NN - 1)
            for (int gg = gn + 1; gg <= NG; gg++) wsi[NOFS_OFF + gg] = NN;
    }

    {                                              // append-scatter (all blocks)
        if (t < 64) cnt[t] = 0;
        __syncthreads();
        int id = gid;
        int bin = 0; unsigned rank = 0; bool act = false;
        if (id < NE + NF) {
            if (id < NE) bin = ldi<I64>(batch, clamp_node(ldi<I64>(ei, id))) & 31;
            else bin = 32 + (ldi<I64>(batch, clamp_node(ldi<I64>(fc, id - NE))) & 31);
            act = true;
            rank = atomicAdd(&cnt[bin], 1u);
        }
        __syncthreads();
        if (t < 64) base[t] = cnt[t] ? atomicAdd(&cur[t], cnt[t]) : 0u;
        __syncthreads();
        if (act) {
            int off = (int)(base[bin] + rank);
            if (bin < 32) {
                if (off < CAPE) {
                    int a = clamp_node(ldi<I64>(ei, id));
                    int b = clamp_node(ldi<I64>(ei, NE + id));
                    float wa = ldf<BF>(nw, a), wb = ldf<BF>(nw, b);
                    float4 ra, rb;
                    ra.x = ldf<BF>(x, 3*a)   * wa;
                    ra.y = ldf<BF>(x, 3*a+1) * wa;
                    ra.z = ldf<BF>(x, 3*a+2) * wa;
                    ra.w = ldf<BF>(ew, id);
                    rb.x = ldf<BF>(x, 3*b)   * wb;
                    rb.y = ldf<BF>(x, 3*b+1) * wb;
                    rb.z = ldf<BF>(x, 3*b+2) * wb;
                    rb.w = 0.0f;
                    float4* dst = er4 + ((size_t)bin * CAPE + off) * 2;
                    dst[0] = ra; dst[1] = rb;
                }
            } else {
                if (off < CAPF) {
                    int fid = id - NE;
                    int a = clamp_node(ldi<I64>(fc, fid));
                    int b = clamp_node(ldi<I64>(fc, NF + fid));
                    int c = clamp_node(ldi<I64>(fc, 2 * NF + fid));
                    float wa = ldf<BF>(nw, a), wb = ldf<BF>(nw, b), wc = ldf<BF>(nw, c);
                    float4 qa, qb, qc;
                    qa.x = ldf<BF>(x, 3*a)   * wa;
                    qa.y = ldf<BF>(x, 3*a+1) * wa;
                    qa.z = ldf<BF>(x, 3*a+2) * wa;
                    qa.w = ldf<BF>(fw, fid);
                    qb.x = ldf<BF>(x, 3*b)   * wb;
                    qb.y = ldf<BF>(x, 3*b+1) * wb;
                    qb.z = ldf<BF>(x, 3*b+2) * wb;
                    qb.w = 0.0f;
                    qc.x = ldf<BF>(x, 3*c)   * wc;
                    qc.y = ldf<BF>(x, 3*c+1) * wc;
                    qc.z = ldf<BF>(x, 3*c+2) * wc;
                    qc.w = 0.0f;
                    float4* dst = fr4 + ((size_t)(bin - 32) * CAPF + off) * 3;
                    dst[0] = qa; dst[1] = qb; dst[2] = qc;
                }
            }
        }
    }
}
__global__ __launch_bounds__(256) void k_pre(const void* __restrict__ x,
                                             const void* __restrict__ nw,
                                             const int* __restrict__ ei,
                                             const int* __restrict__ fc,
                                             const int* __restrict__ batch,
                                             const void* __restrict__ ew,
                                             const void* __restrict__ fw,
                                             float* __restrict__ wsf,
                                             int* __restrict__ wsi,
                                             unsigned* __restrict__ cur,
                                             float4* __restrict__ er4,
                                             float4* __restrict__ fr4) {
    __shared__ unsigned cnt[64], base[64];
    bool bf = detect_bf(x), i64 = detect_i64(ei);
    if (bf)  { if (i64) pre_body<true,true >(x,nw,ei,fc,batch,ew,fw,wsf,wsi,cur,er4,fr4,cnt,base);
               else     pre_body<true,false>(x,nw,ei,fc,batch,ew,fw,wsf,wsi,cur,er4,fr4,cnt,base); }
    else     { if (i64) pre_body<false,true >(x,nw,ei,fc,batch,ew,fw,wsf,wsi,cur,er4,fr4,cnt,base);
               else     pre_body<false,false>(x,nw,ei,fc,batch,ew,fw,wsf,wsi,cur,er4,fr4,cnt,base); }
}

// K1: ecc via wave-private LDS delta-histograms (4 copies, plain RMW).
// Gather-free: heights computed on the fly from premultiplied records
// (sequential uniform 32/48B loads) against v[:,d] held in 3 VGPRs.
// float4 LDS zero/collapse; parallel segmented-prefix epilogue.
template<bool BF>
__device__ __forceinline__ void ecc_body(const void* xx, const void* nw, const void* vv,
                                         const int* wsi, const unsigned* cur,
                                         float* eccf, const float4* er4,
                                         const float4* fr4, float* hist) {
    int t = threadIdx.x;
    int d = t & 63;
    int w = __builtin_amdgcn_readfirstlane(t) >> 6;
    int g  = blockIdx.x >> 5;                 // / CHB
    int cb = blockIdx.x & (CHB - 1);
    int sid = cb * 4 + w;
    const int S = CHB * 4;                    // 128 streams per graph

    float v0 = ldf<BF>(vv, d), v1 = ldf<BF>(vv, ND + d), v2 = ldf<BF>(vv, 2 * ND + d);

    float4* h4 = (float4*)hist;
    const int Q = HBINS * 16;                 // 624 float4 per copy
    float4 z; z.x = z.y = z.z = z.w = 0.0f;
    for (int j = t; j < 4 * Q; j += 256) h4[j] = z;
    __syncthreads();

    float* hb = hist + w * (HBINS * 64) + d;  // wave-private copy, lane-owned column

    // nodes (+1): heights from x,nw directly (uniform loads), unroll 2
    int ns = wsi[NOFS_OFF + g], nend = wsi[NOFS_OFF + g + 1];
    int i = ns + sid;
    for (; i + S < nend; i += 2 * S) {
        int j = i + S;
        float a0 = ldf<BF>(xx, 3*i), a1 = ldf<BF>(xx, 3*i+1), a2 = ldf<BF>(xx, 3*i+2);
        float wa = ldf<BF>(nw, i);
        float b0 = ldf<BF>(xx, 3*j), b1v = ldf<BF>(xx, 3*j+1), b2v = ldf<BF>(xx, 3*j+2);
        float wb = ldf<BF>(nw, j);
        accum_hist(fmaf(a2, v2, fmaf(a1, v1, a0 * v0)) * wa, 1.0f, hb);
        accum_hist(fmaf(b2v, v2, fmaf(b1v, v1, b0 * v0)) * wb, 1.0f, hb);
    }
    for (; i < nend; i += S) {
        float a0 = ldf<BF>(xx, 3*i), a1 = ldf<BF>(xx, 3*i+1), a2 = ldf<BF>(xx, 3*i+2);
        float wa = ldf<BF>(nw, i);
        accum_hist(fmaf(a2, v2, fmaf(a1, v1, a0 * v0)) * wa, 1.0f, hb);
    }

    // edges (-1): 2 float4 per record, unroll 2
    int ecnt = min((int)cur[g], CAPE);
    const float4* eg = er4 + (size_t)g * CAPE * 2;
    i = sid;
    for (; i + S < ecnt; i += 2 * S) {
        float4 pa1 = eg[2*i],       pb1 = eg[2*i + 1];
        float4 pa2 = eg[2*(i+S)],   pb2 = eg[2*(i+S) + 1];
        float h1 = fmaxf(dot3w(pa1, v0, v1, v2), dot3w(pb1, v0, v1, v2)) * pa1.w;
        float h2 = fmaxf(dot3w(pa2, v0, v1, v2), dot3w(pb2, v0, v1, v2)) * pa2.w;
        accum_hist(h1, -1.0f, hb);
        accum_hist(h2, -1.0f, hb);
    }
    for (; i < ecnt; i += S) {
        float4 pa = eg[2*i], pb = eg[2*i + 1];
        accum_hist(fmaxf(dot3w(pa, v0, v1, v2), dot3w(pb, v0, v1, v2)) * pa.w,
                   -1.0f, hb);
    }

    // faces (+1): 3 float4 per record, unroll 2
    int fcnt = min((int)cur[32 + g], CAPF);
    const float4* fg = fr4 + (size_t)g * CAPF * 3;
    i = sid;
    for (; i + S < fcnt; i += 2 * S) {
        float4 qa1 = fg[3*i], qb1 = fg[3*i + 1], qc1 = fg[3*i + 2];
        float4 qa2 = fg[3*(i+S)], qb2 = fg[3*(i+S) + 1], qc2 = fg[3*(i+S) + 2];
        float h1 = fmaxf(fmaxf(dot3w(qa1, v0, v1, v2), dot3w(qb1, v0, v1, v2)),
                         dot3w(qc1, v0, v1, v2)) * qa1.w;
        float h2 = fmaxf(fmaxf(dot3w(qa2, v0, v1, v2), dot3w(qb2, v0, v1, v2)),
                         dot3w(qc2, v0, v1, v2)) * qa2.w;
        accum_hist(h1, 1.0f, hb);
        accum_hist(h2, 1.0f, hb);
    }
    for (; i < fcnt; i += S) {
        float4 qa = fg[3*i], qb = fg[3*i + 1], qc = fg[3*i + 2];
        accum_hist(fmaxf(fmaxf(dot3w(qa, v0, v1, v2), dot3w(qb, v0, v1, v2)),
                         dot3w(qc, v0, v1, v2)) * qa.w, 1.0f, hb);
    }

    __syncthreads();
    // collapse 4 wave copies into copy 0 (float4)
    for (int o = t; o < Q; o += 256) {
        float4 A = h4[o], B = h4[Q + o], C = h4[2*Q + o], D = h4[3*Q + o];
        A.x += B.x + C.x + D.x;  A.y += B.y + C.y + D.y;
        A.z += B.z + C.z + D.z;  A.w += B.w + C.w + D.w;
        h4[o] = A;
    }
    __syncthreads();
    // parallel segmented prefix: wave w owns bins [8w, 8w+8); copy 1 reused
    // as cross-wave segment-sum scratch (dead after collapse).
    {
        float* segw = hist + HBINS * 64;
        float run = 0.0f, pre[8];
#pragma unroll
        for (int jj = 0; jj < 8; jj++) {
            run += hist[(4 + w * 8 + jj) * 64 + d];
            pre[jj] = run;
        }
        float padb = hist[d] + hist[64 + d] + hist[128 + d] + hist[192 + d];
        segw[w * 64 + d] = run;
        __syncthreads();
        float base = padb;
#pragma unroll
        for (int u = 0; u < 3; u++) if (u < w) base += segw[u * 64 + d];
        float* eb = eccf + g * (NB * ND) + d;
#pragma unroll
        for (int jj = 0; jj < 8; jj++)
            unsafeAtomicAdd(eb + (w * 8 + jj) * 64, base + pre[jj]);
    }
}
__global__ __launch_bounds__(256, 4) void k_ecc(const void* __restrict__ x,
                                                const void* __restrict__ nw,
                                                const void* __restrict__ v,
                                                const int* __restrict__ wsi,
                                                const unsigned* __restrict__ cur,
                                                float* __restrict__ eccf,
                                                const float4* __restrict__ er4,
                                                const float4* __restrict__ fr4) {
    __shared__ float hist[4 * HBINS * 64];         // 39.9 KB; 4 blocks/CU
    if (detect_bf(x)) ecc_body<true >(x, nw, v, wsi, cur, eccf, er4, fr4, hist);
    else              ecc_body<false>(x, nw, v, wsi, cur, eccf, er4, fr4, hist);
}

// K2: MLP layer 1 + flat flush + last-block-per-graph fused layer 2.
// Handoff via coherence-point atomics ONLY (relaxed agent-scope atomic
// store/load + relaxed done-counter RMW; ordering from __syncthreads'
// vmcnt(0) drain). NO __threadfence (R3 lesson: agent fence = per-block
// L2 writeback on gfx950, ~10 us over 256 blocks).
// LDS reduce layout conflict-free (R6 lesson): red[r*280 + s8*33 + i]
// gives <=2 lanes/bank on both write and read (2-way is free on CDNA).
template<bool BF>
__device__ __forceinline__ void mlp_body(const void* W1, const void* b1,
                                         const void* W2, const void* b2,
                                         const float* eccf, float* hbuf,
                                         unsigned* done, void* outv,
                                         float* red, float* pr, unsigned* lastflag) {
    int g = blockIdx.x >> 3, hc = blockIdx.x & 7;
    int t = threadIdx.x;

    const float4* fp = (const float4*)(eccf + g * (NB * ND) + t * 8);
    float4 fa = fp[0], fb = fp[1];
    float fl[8] = {fa.x, fa.y, fa.z, fa.w, fb.x, fb.y, fb.z, fb.w};

    if (hc == 0) {                              // flush flat output (once per graph)
        int ob = NG * NCLS + g * (NB * ND) + t * 8;
        if (BF) {
#pragma unroll
            for (int j = 0; j < 8; j++)
                ((__hip_bfloat16*)outv)[ob + j] = __float2bfloat16(fl[j]);
        } else {
            ((float4*)((float*)outv + ob))[0] = fa;
            ((float4*)((float*)outv + ob))[1] = fb;
        }
    }

    float acc[32];
#pragma unroll
    for (int r = 0; r < 32; r++) acc[r] = 0.0f;
#pragma unroll 4
    for (int r = 0; r < 32; r++) {
        size_t wb = (size_t)(hc * 32 + r) * (NB * ND) + t * 8;
        float wv[8];
        if (BF) {
            uint4 u = *(const uint4*)((const __hip_bfloat16*)W1 + wb);
            wv[0] = __uint_as_float(u.x << 16); wv[1] = __uint_as_float(u.x & 0xffff0000u);
            wv[2] = __uint_as_float(u.y << 16); wv[3] = __uint_as_float(u.y & 0xffff0000u);
            wv[4] = __uint_as_float(u.z << 16); wv[5] = __uint_as_float(u.z & 0xffff0000u);
            wv[6] = __uint_as_float(u.w << 16); wv[7] = __uint_as_float(u.w & 0xffff0000u);
        } else {
            float4 a = *(const float4*)((const float*)W1 + wb);
            float4 b = *(const float4*)((const float*)W1 + wb + 4);
            wv[0]=a.x; wv[1]=a.y; wv[2]=a.z; wv[3]=a.w;
            wv[4]=b.x; wv[5]=b.y; wv[6]=b.z; wv[7]=b.w;
        }
        float s = 0.0f;
#pragma unroll
        for (int j = 0; j < 8; j++) s = fmaf(wv[j], fl[j], s);
        acc[r] = s;
    }

    {   // conflict-free transpose-reduce: source thread t -> (s8=t>>5, i=t&31)
        int base_w = (t >> 5) * 33 + (t & 31);
#pragma unroll
        for (int r = 0; r < 32; r++) red[r * 280 + base_w] = acc[r];
    }
    __syncthreads();
    {
        int r = t >> 3, s8 = t & 7;
        const float* row = red + r * 280 + s8 * 33;
        float sum = 0.0f;
#pragma unroll
        for (int i = 0; i < 32; i++) sum += row[i];
        pr[r * 8 + s8] = sum;
    }
    __syncthreads();
    if (t < 32) {
        float h = ldf<BF>(b1, hc * 32 + t);
#pragma unroll
        for (int s8 = 0; s8 < 8; s8++) h += pr[t * 8 + s8];
        // write-through atomic store: visible at coherence point, no dirty L2 line
        __hip_atomic_store(&hbuf[g * HIDN + hc * 32 + t], fmaxf(h, 0.0f),
                           __ATOMIC_RELAXED, __HIP_MEMORY_SCOPE_AGENT);
    }

    // ---- last-block-per-graph fused layer 2 (fence-free handoff) ----
    __syncthreads();                            // implies vmcnt(0) drain: stores done
    if (t == 0) {
        unsigned prev = __hip_atomic_fetch_add(&done[g], 1u, __ATOMIC_RELAXED,
                                               __HIP_MEMORY_SCOPE_AGENT);
        *lastflag = (prev == 7u) ? 1u : 0u;
    }
    __syncthreads();
    if (*lastflag) {
        // sc-bypass loads: cannot hit a stale local L2 line
        red[t] = __hip_atomic_load(&hbuf[g * HIDN + t], __ATOMIC_RELAXED,
                                   __HIP_MEMORY_SCOPE_AGENT);
        __syncthreads();
        int w = t >> 6, lane = t & 63;
        for (int c = w; c < NCLS; c += 4) {
            float p = red[lane]        * ldf<BF>(W2, c * HIDN + lane)
                    + red[lane + 64]   * ldf<BF>(W2, c * HIDN + lane + 64)
                    + red[lane + 128]  * ldf<BF>(W2, c * HIDN + lane + 128)
                    + red[lane + 192]  * ldf<BF>(W2, c * HIDN + lane + 192);
#pragma unroll
            for (int off = 32; off >= 1; off >>= 1) p += __shfl_xor(p, off);
            if (lane == 0) {
                float r = p + ldf<BF>(b2, c);
                if (BF) ((__hip_bfloat16*)outv)[g * NCLS + c] = __float2bfloat16(r);
                else    ((float*)outv)[g * NCLS + c] = r;
            }
        }
    }
}
__global__ __launch_bounds__(256) void k_mlp(const void* __restrict__ W1,
                                             const void* __restrict__ b1,
                                             const void* __restrict__ W2,
                                             const void* __restrict__ b2,
                                             const float* __restrict__ eccf,
                                             float* __restrict__ hbuf,
                                             unsigned* __restrict__ done,
                                             void* __restrict__ outv,
                                             const void* __restrict__ x) {
    __shared__ float red[32 * 280];                 // 35 KB, conflict-free layout
    __shared__ float pr[256];
    __shared__ unsigned lastflag;
    if (detect_bf(x)) mlp_body<true >(W1, b1, W2, b2, eccf, hbuf, done, outv, red, pr, &lastflag);
    else              mlp_body<false>(W1, b1, W2, b2, eccf, hbuf, done, outv, red, pr, &lastflag);
}

extern "C" void kernel_launch(void* const* d_in, const int* in_sizes, int n_in,
                              void* d_out, int out_size, void* d_ws, size_t ws_size,
                              hipStream_t stream) {
    const void* x  = d_in[0];
    const void* nw = d_in[1];
    const void* ew = d_in[2];
    const void* fw = d_in[3];
    const void* v  = d_in[4];
    const void* W1 = d_in[5];
    const void* b1 = d_in[6];
    const void* W2 = d_in[7];
    const void* b2 = d_in[8];
    const int* ei    = (const int*)d_in[9];
    const int* fc    = (const int*)d_in[10];
    const int* batch = (const int*)d_in[11];

    float*    wsf = (float*)d_ws;
    unsigned* wsu = (unsigned*)d_ws;
    int*      wsi = (int*)d_ws;
    float*    eccf = wsf + ECCF_OFF;
    unsigned* cur  = wsu + CUR_OFF;
    unsigned* done = wsu + DONE_OFF;
    float*    hbuf = wsf + HB_OFF;
    float4*   er4  = (float4*)(wsf + ER_OFF);
    float4*   fr4  = (float4*)(wsf + FR_OFF);

    // zero cursors + boundaries pad + done counters (544 B)
    hipMemsetAsync((char*)d_ws + (size_t)CUR_OFF * 4, 0, MS_WORDS * 4, stream);

    k_pre<<<PREB, 256, 0, stream>>>(x, nw, ei, fc, batch, ew, fw, wsf, wsi, cur, er4, fr4);
    k_ecc<<<NG * CHB, 256, 0, stream>>>(x, nw, v, wsi, cur, eccf, er4, fr4);
    k_mlp<<<NG * 8, 256, 0, stream>>>(W1, b1, W2, b2, eccf, hbuf, done, d_out, x);
}